// Round 8
// baseline (188.476 us; speedup 1.0000x reference)
//
#include <hip/hip_runtime.h>
#include <cstdint>
#include <cstddef>

// DecayAttention: B=2, T=2048, C=1024, H=16, DH=64
// out = proj( softmax( (QK^T * scale) * exp(-softplus(lambda_h)*|i-j|) ) V )

#define DEVI __device__ __forceinline__

typedef float f32x4 __attribute__((ext_vector_type(4)));
typedef short bf16x8 __attribute__((ext_vector_type(8)));

static constexpr int Bc = 2, Tc = 2048, Cc = 1024, Hc = 16, DHc = 64;

DEVI unsigned short f2bf(float f) {
  union { float f; unsigned u; } a; a.f = f;
  unsigned u = a.u;
  unsigned r = (u + 0x7fffu + ((u >> 16) & 1u)) >> 16;  // RNE
  return (unsigned short)r;
}

DEVI float bf2f(unsigned short u) {
  union { unsigned u; float f; } a; a.u = ((unsigned)u) << 16;
  return a.f;
}

DEVI unsigned packbf(float lo, float hi) {
  return (unsigned)f2bf(lo) | ((unsigned)f2bf(hi) << 16);
}

DEVI void gload_lds16(const void* g, void* l) {
  __builtin_amdgcn_global_load_lds(
      (const __attribute__((address_space(1))) void*)g,
      (__attribute__((address_space(3))) void*)l, 16, 0, 0);
}

// ---------------------------------------------------------------- f32 -> bf16
__global__ __launch_bounds__(256) void k_cvt(const float* __restrict__ in,
                                             unsigned short* __restrict__ out,
                                             int n4) {
  int i = blockIdx.x * 256 + threadIdx.x;
  if (i >= n4) return;
  const float4 v = ((const float4*)in)[i];
  ushort4 o;
  o.x = f2bf(v.x); o.y = f2bf(v.y); o.z = f2bf(v.z); o.w = f2bf(v.w);
  ((ushort4*)out)[i] = o;
}

// ------------------------------------------------- NT GEMM: C = A * B^T + bias
// 128x128 tile, 4 waves — kept for gemm2 (proven, full-grid at N=1024).
template <int OUT_BF16>
__global__ __launch_bounds__(256) void k_gemm_nt(
    const unsigned short* __restrict__ A, const unsigned short* __restrict__ B,
    const float* __restrict__ bias, void* __restrict__ C, int K, int ldc) {
  __shared__ __align__(16) unsigned short As[128 * 32];
  __shared__ __align__(16) unsigned short Bs[128 * 32];
  const int tid = threadIdx.x, lane = tid & 63, wid = tid >> 6;
  const int wm = wid >> 1, wn = wid & 1;
  const int l15 = lane & 15, l4 = lane >> 4;
  f32x4 acc[4][4] = {};
  const int boff0 = wid * 2048 + lane * 16;  // staging byte offset (2 segs/wave)
  for (int k0 = 0; k0 < K; k0 += 32) {
    __syncthreads();
#pragma unroll
    for (int s = 0; s < 2; ++s) {
      const int boff = boff0 + s * 1024;
      const int row = boff >> 6, colb = boff & 63;  // 64 B per LDS row (32 bf16)
      gload_lds16((const char*)A + ((size_t)(blockIdx.y * 128 + row) * K + k0) * 2 + colb,
                  (char*)As + (wid * 2 + s) * 1024);
      gload_lds16((const char*)B + ((size_t)(blockIdx.x * 128 + row) * K + k0) * 2 + colb,
                  (char*)Bs + (wid * 2 + s) * 1024);
    }
    __syncthreads();
    bf16x8 af[4], bf[4];
#pragma unroll
    for (int i = 0; i < 4; ++i) {
      af[i] = *(const bf16x8*)(As + (wm * 64 + i * 16 + l15) * 32 + l4 * 8);
      bf[i] = *(const bf16x8*)(Bs + (wn * 64 + i * 16 + l15) * 32 + l4 * 8);
    }
#pragma unroll
    for (int mi = 0; mi < 4; ++mi)
#pragma unroll
      for (int ni = 0; ni < 4; ++ni)
        acc[mi][ni] = __builtin_amdgcn_mfma_f32_16x16x32_bf16(af[mi], bf[ni],
                                                              acc[mi][ni], 0, 0, 0);
  }
#pragma unroll
  for (int mi = 0; mi < 4; ++mi) {
    const int r0 = blockIdx.y * 128 + wm * 64 + mi * 16 + l4 * 4;
#pragma unroll
    for (int ni = 0; ni < 4; ++ni) {
      const int c = blockIdx.x * 128 + wn * 64 + ni * 16 + l15;
      const float bv = bias[c];
#pragma unroll
      for (int j = 0; j < 4; ++j) {
        const float v = acc[mi][ni][j] + bv;
        if (OUT_BF16)
          ((unsigned short*)C)[(size_t)(r0 + j) * ldc + c] = f2bf(v);
        else
          ((float*)C)[(size_t)(r0 + j) * ldc + c] = v;
      }
    }
  }
}

// --------------------- 256x256-tile NT GEMM, 8 waves, BK=64, phase-interleaved
// Race-freedom by construction: phase (qm,qn) reads only A-half qm / B-half qn
// (wave outputs are strided: two 64-row stripes x two 32-col stripes). The half
// staged in phase p was last read in phase p-1, and stages are issued after the
// post-MFMA barrier of p-1 (all waves' lgkm drains precede it). Staging order
// per tile t: p1 Abot(t+1)->dbuf^1, p2 Bbot(t+1)->dbuf^1, p3 Atop(t+2)->dbuf,
// p4 Btop(t+2)->dbuf + vmcnt(4) (all but newest 2 half-tiles landed => all of
// tile t+1 in LDS before its phase-1 reads). Tail: vmcnt(0) when stages stop.
// T2 swizzle: LDS 16B-unit (row,u) holds global unit (row, u^(row&7)); linear
// gload_lds dest + pre-swizzled global source; ds_read applies same XOR.
template <int OUT_BF16>
__global__ __launch_bounds__(512, 2) void k_gemm256(
    const unsigned short* __restrict__ A, const unsigned short* __restrict__ B,
    const float* __restrict__ bias, void* __restrict__ C,
    int K, int ldc, int NB) {
  __shared__ __align__(16) unsigned short AS[2][2][8192];  // [dbuf][half][128*64]
  __shared__ __align__(16) unsigned short BS[2][2][8192];
  const int tid = threadIdx.x, lane = tid & 63, wid = tid >> 6;
  const int wm = wid >> 2, wn = wid & 3;
  const int l15 = lane & 15, l4 = lane >> 4;
  // XCD-aware swizzle (gridDim.x % 8 == 0)
  const int swz = (blockIdx.x & 7) * (gridDim.x >> 3) + (blockIdx.x >> 3);
  const int blockM = (swz / NB) * 256, blockN = (swz % NB) * 256;

  // staging: per wave 2 gloads per half-tile (1 KB each, linear LDS dest)
  const unsigned short* aS[2];
  const unsigned short* bS[2];
  char* aD[2]; char* bD[2];
#pragma unroll
  for (int g = 0; g < 2; ++g) {
    const int r = wid * 16 + g * 8 + (lane >> 3);
    const int cu = ((lane & 7) ^ (r & 7)) * 8;  // pre-swizzled source unit
    aS[g] = A + (size_t)(blockM + r) * K + cu;
    bS[g] = B + (size_t)(blockN + r) * K + cu;
    aD[g] = (char*)&AS[0][0][(wid * 2 + g) * 512];
    bD[g] = (char*)&BS[0][0][(wid * 2 + g) * 512];
  }
  const int T = K >> 6;

#define SG_A(d, h, t)                                                          \
  do { _Pragma("unroll") for (int g = 0; g < 2; ++g)                           \
    gload_lds16(aS[g] + (size_t)(h) * 128 * K + (t) * 64,                      \
                aD[g] + ((d) * 2 + (h)) * 16384); } while (0)
#define SG_B(d, h, t)                                                          \
  do { _Pragma("unroll") for (int g = 0; g < 2; ++g)                           \
    gload_lds16(bS[g] + (size_t)(h) * 128 * K + (t) * 64,                      \
                bD[g] + ((d) * 2 + (h)) * 16384); } while (0)

  // ds_read byte offsets (swizzle-inverted), loop-invariant
  int aoff[4][2], boff[2][2];
#pragma unroll
  for (int mt = 0; mt < 4; ++mt)
#pragma unroll
    for (int kh = 0; kh < 2; ++kh) {
      const int r = wm * 64 + mt * 16 + l15;
      aoff[mt][kh] = r * 128 + (((kh * 4 + l4) ^ (r & 7)) * 16);
    }
#pragma unroll
  for (int nt = 0; nt < 2; ++nt)
#pragma unroll
    for (int kh = 0; kh < 2; ++kh) {
      const int r = wn * 32 + nt * 16 + l15;
      boff[nt][kh] = r * 128 + (((kh * 4 + l4) ^ (r & 7)) * 16);
    }

  f32x4 acc[8][4] = {};

  // prologue: tile0 fully + tile1 top halves; all of tile0 landed
  SG_A(0, 0, 0); SG_B(0, 0, 0); SG_A(0, 1, 0); SG_B(0, 1, 0);
  if (T > 1) {
    SG_A(1, 0, 1); SG_B(1, 0, 1);
    asm volatile("s_waitcnt vmcnt(4)" ::: "memory");
  } else {
    asm volatile("s_waitcnt vmcnt(0)" ::: "memory");
  }
  __builtin_amdgcn_s_barrier();
  __builtin_amdgcn_sched_barrier(0);

#define PHASE(d, qm, qn, STG, VMODE)                                           \
  do {                                                                         \
    const char* aL = (const char*)&AS[d][qm][0];                               \
    const char* bL = (const char*)&BS[d][qn][0];                               \
    bf16x8 af[4][2], bfr[2][2];                                                \
    _Pragma("unroll") for (int mt = 0; mt < 4; ++mt)                           \
      _Pragma("unroll") for (int kh = 0; kh < 2; ++kh)                         \
        af[mt][kh] = *(const bf16x8*)(aL + aoff[mt][kh]);                      \
    _Pragma("unroll") for (int nt = 0; nt < 2; ++nt)                           \
      _Pragma("unroll") for (int kh = 0; kh < 2; ++kh)                         \
        bfr[nt][kh] = *(const bf16x8*)(bL + boff[nt][kh]);                     \
    STG;                                                                       \
    if ((VMODE) == 1) asm volatile("s_waitcnt vmcnt(4)" ::: "memory");         \
    if ((VMODE) == 2) asm volatile("s_waitcnt vmcnt(0)" ::: "memory");         \
    __builtin_amdgcn_s_barrier();                                              \
    asm volatile("s_waitcnt lgkmcnt(0)" ::: "memory");                         \
    __builtin_amdgcn_sched_barrier(0);                                         \
    __builtin_amdgcn_s_setprio(1);                                             \
    _Pragma("unroll") for (int mt = 0; mt < 4; ++mt)                           \
      _Pragma("unroll") for (int nt = 0; nt < 2; ++nt) {                       \
        f32x4& ac = acc[(qm) * 4 + mt][(qn) * 2 + nt];                         \
        ac = __builtin_amdgcn_mfma_f32_16x16x32_bf16(af[mt][0], bfr[nt][0], ac, 0, 0, 0); \
        ac = __builtin_amdgcn_mfma_f32_16x16x32_bf16(af[mt][1], bfr[nt][1], ac, 0, 0, 0); \
      }                                                                        \
    __builtin_amdgcn_s_setprio(0);                                             \
    __builtin_amdgcn_s_barrier();                                              \
    __builtin_amdgcn_sched_barrier(0);                                         \
  } while (0)

  for (int t = 0; t < T; ++t) {
    const int d = t & 1;
    PHASE(d, 0, 0, if (t + 1 < T) SG_A(d ^ 1, 1, t + 1), 0);
    PHASE(d, 0, 1, if (t + 1 < T) SG_B(d ^ 1, 1, t + 1), 0);
    PHASE(d, 1, 0, if (t + 2 < T) SG_A(d, 0, t + 2), 0);
    PHASE(d, 1, 1, if (t + 2 < T) SG_B(d, 0, t + 2), (t + 2 < T) ? 1 : 2);
  }
#undef PHASE
#undef SG_A
#undef SG_B

  // epilogue: wave rows = {qm*128 + wm*64 + mt*16}, cols = {qn*128 + wn*32 + nt*16}
#pragma unroll
  for (int m = 0; m < 8; ++m) {
    const int r0 = blockM + (m >> 2) * 128 + wm * 64 + (m & 3) * 16 + l4 * 4;
#pragma unroll
    for (int n = 0; n < 4; ++n) {
      const int c = blockN + (n >> 1) * 128 + wn * 32 + (n & 1) * 16 + l15;
      const float bv = bias[c];
#pragma unroll
      for (int j = 0; j < 4; ++j) {
        const float v = acc[m][n][j] + bv;
        if (OUT_BF16)
          ((unsigned short*)C)[(size_t)(r0 + j) * ldc + c] = f2bf(v);
        else
          ((float*)C)[(size_t)(r0 + j) * ldc + c] = v;
      }
    }
  }
}

// --------- V transpose: [B,T,H,DH] -> [B,H,DH,T], plus per-64-key-tile V sums
__global__ __launch_bounds__(256) void k_vtrans(const unsigned short* __restrict__ qkv,
                                                unsigned short* __restrict__ vt,
                                                float* __restrict__ vsum) {
  __shared__ unsigned short tile[64][65];
  __shared__ float psum[4][64];
  const int bh = blockIdx.y, b = bh >> 4, h = bh & 15;
  const int t0 = blockIdx.x * 64;
  const int tid = threadIdx.x;
#pragma unroll
  for (int r = 0; r < 16; ++r) {
    const int e = r * 256 + tid;
    const int row = e >> 6, col = e & 63;  // row = t offset, col = d
    tile[row][col] = qkv[(size_t)(b * Tc + t0 + row) * (3 * Cc) + 2 * Cc + h * DHc + col];
  }
  __syncthreads();
#pragma unroll
  for (int r = 0; r < 16; ++r) {
    const int e = r * 256 + tid;
    const int dd = e >> 6, tcol = e & 63;
    vt[((size_t)bh * DHc + dd) * Tc + t0 + tcol] = tile[tcol][dd];
  }
  // per-tile V column sums (for far-field prefix)
  const int d = tid & 63, part = tid >> 6;
  float s = 0.f;
#pragma unroll
  for (int k = 0; k < 16; ++k) s += bf2f(tile[part * 16 + k][d]);
  psum[part][d] = s;
  __syncthreads();
  if (tid < 64)
    vsum[((size_t)bh * 32 + blockIdx.x) * 64 + tid] =
        psum[0][tid] + psum[1][tid] + psum[2][tid] + psum[3][tid];
}

// --------------- prefix over key tiles: vpre[bh][t][d] = sum_{k<64t} V[k][d]
__global__ __launch_bounds__(64) void k_prefix(const float* __restrict__ vsum,
                                               float* __restrict__ vpre) {
  const int bh = blockIdx.x, d = threadIdx.x;
  float run = 0.f;
  for (int t = 0; t < 32; ++t) {
    vpre[((size_t)bh * 33 + t) * 64 + d] = run;
    run += vsum[((size_t)bh * 32 + t) * 64 + d];
  }
  vpre[((size_t)bh * 33 + 32) * 64 + d] = run;
}

// --------------------------------------------------------- decay attention
// R7 structure (unchanged): far-field cutoff + LDS-staged K/V + swapped-operand
// S^T = mfma(K,Q) + P^T->B-frag via shuffles + no max-subtraction.
__global__ __launch_bounds__(256, 2) void k_attn(const unsigned short* __restrict__ qkv,
                                                 const unsigned short* __restrict__ vt,
                                                 const float* __restrict__ lraw,
                                                 const float* __restrict__ vpre,
                                                 unsigned short* __restrict__ ao) {
  __shared__ __align__(16) unsigned short Ks[2][4096];  // [64 keys][64 d] swz
  __shared__ __align__(16) unsigned short Vs[2][4096];  // [64 d][64 keys] swz
  const int tid = threadIdx.x, lane = tid & 63, wid = tid >> 6;
  const int l15 = lane & 15, l4 = lane >> 4;
  const int bid = blockIdx.x;
  const int xcd = bid & 7, jj = bid >> 3;
  const int bh = xcd + 8 * (jj >> 4);   // 0..31
  const int qblk = jj & 15;             // 0..15
  const int b = bh >> 4, h = bh & 15;
  const float lam = log1pf(__expf(lraw[h]));  // softplus
  const int qt0 = qblk * 8 + wid * 2;   // wave's q-tiles: qt0, qt0+1
  const int qA = qt0 * 16 + l15, qB = qA + 16;

  // ---- far-field band
  const int Dstar = (int)fminf(2048.0f, ceilf(18.5f / lam));
  const int q0 = qblk * 128;
  const int t_lo = (q0 > Dstar) ? ((q0 - Dstar) >> 6) : 0;
  const int t_end = min(32, (q0 + Dstar + 191) >> 6);  // first fully-far upper tile
  const int nfar = 64 * t_lo + (Tc - 64 * t_end);      // keys with p == 1 exactly

  // Q fragments (B-operand): col=q (l15), k=d=l4*8+j
  const unsigned short* qpA = qkv + (size_t)(b * Tc + qA) * (3 * Cc) + h * DHc + l4 * 8;
  const unsigned short* qpB = qkv + (size_t)(b * Tc + qB) * (3 * Cc) + h * DHc + l4 * 8;
  const bf16x8 qfA0 = *(const bf16x8*)qpA, qfA1 = *(const bf16x8*)(qpA + 32);
  const bf16x8 qfB0 = *(const bf16x8*)qpB, qfB1 = *(const bf16x8*)(qpB + 32);

  // ---- staging source pointers (per-lane, pre-swizzled global addresses)
  const unsigned short* kSrc[2];
  const unsigned short* vSrc[2];
#pragma unroll
  for (int rr = 0; rr < 2; ++rr) {
    const int slot = (rr * 4 + wid) * 64 + lane;  // 0..511
    const int row = slot >> 3, wu = slot & 7;
    kSrc[rr] = qkv + (size_t)(b * Tc + row) * (3 * Cc) + Cc + h * DHc + 8 * (wu ^ (row & 7));
    vSrc[rr] = vt + (size_t)(bh * DHc + row) * Tc + 8 * (wu ^ (row & 7));
  }
  constexpr size_t KTS = (size_t)64 * 3 * Cc;  // K elems per 64-key tile
  int koffs[2][4], voffs[2][4];
#pragma unroll
  for (int hf = 0; hf < 2; ++hf) {
    const int r0 = hf * 32 + l15, r1 = r0 + 16;
    koffs[hf][0] = r0 * 128 + ((l4 ^ (r0 & 7)) * 16);
    koffs[hf][1] = r0 * 128 + (((4 + l4) ^ (r0 & 7)) * 16);
    koffs[hf][2] = r1 * 128 + ((l4 ^ (r1 & 7)) * 16);
    koffs[hf][3] = r1 * 128 + (((4 + l4) ^ (r1 & 7)) * 16);
#pragma unroll
    for (int db = 0; db < 4; ++db) {
      const int rv = db * 16 + l15;
      voffs[hf][db] = rv * 128 + (((hf * 4 + l4) ^ (rv & 7)) * 16);
    }
  }

  const int src0 = l15 | ((l4 & 1) << 5);
  const bool hi = (l4 >= 2);

  // ---- seed O with far-field V sums (weight exactly 1), lsum with far count
  f32x4 oA[4], oB[4];
  {
    const float* pre_lo = vpre + ((size_t)bh * 33 + t_lo) * 64;
    const float* pre_hi = vpre + ((size_t)bh * 33 + t_end) * 64;
    const float* pre_all = vpre + ((size_t)bh * 33 + 32) * 64;
#pragma unroll
    for (int di = 0; di < 4; ++di)
#pragma unroll
      for (int j = 0; j < 4; ++j) {
        const int d = di * 16 + l4 * 4 + j;
        const float far = pre_lo[d] + (pre_all[d] - pre_hi[d]);
        oA[di][j] = far;
        oB[di][j] = far;
      }
  }
  float lsumA = 0.f, lsumB = 0.f;

#define STAGE(bb, t)                                                          \
  do {                                                                        \
    _Pragma("unroll") for (int rr = 0; rr < 2; ++rr) {                        \
      gload_lds16(kSrc[rr] + (size_t)(t) * KTS, &Ks[bb][(rr * 4 + wid) * 512]); \
      gload_lds16(vSrc[rr] + (t) * 64, &Vs[bb][(rr * 4 + wid) * 512]);        \
    }                                                                         \
  } while (0)

#define QTILE_P(zz0, zz1, delta_, lsum_, pf_)                                 \
  do {                                                                        \
    float p0[4], p1[4];                                                       \
    _Pragma("unroll") for (int r = 0; r < 4; ++r) {                           \
      const float d0 = 0.125f * __expf(-lam * (float)abs((delta_) - r));      \
      const float d1 = 0.125f * __expf(-lam * (float)abs((delta_) - 16 - r)); \
      p0[r] = __expf(zz0[r] * d0);                                            \
      p1[r] = __expf(zz1[r] * d1);                                            \
      lsum_ += p0[r] + p1[r];                                                 \
    }                                                                         \
    const unsigned pk00 = packbf(p0[0], p0[1]);                               \
    const unsigned pk01 = packbf(p0[2], p0[3]);                               \
    const unsigned pk10 = packbf(p1[0], p1[1]);                               \
    const unsigned pk11 = packbf(p1[2], p1[3]);                               \
    const unsigned a0 = __shfl(pk00, src0, 64), b0 = __shfl(pk10, src0, 64);  \
    const unsigned a1 = __shfl(pk01, src0, 64), b1 = __shfl(pk11, src0, 64);  \
    const unsigned a2 = __shfl(pk00, src0 + 16, 64),                          \
                   b2 = __shfl(pk10, src0 + 16, 64);                          \
    const unsigned a3 = __shfl(pk01, src0 + 16, 64),                          \
                   b3 = __shfl(pk11, src0 + 16, 64);                          \
    pf_.u[0] = hi ? b0 : a0;                                                  \
    pf_.u[1] = hi ? b1 : a1;                                                  \
    pf_.u[2] = hi ? b2 : a2;                                                  \
    pf_.u[3] = hi ? b3 : a3;                                                  \
  } while (0)

#define COMPUTE(bb, kb0)                                                          \
  do {                                                                            \
    const char* kL = (const char*)&Ks[bb][0];                                     \
    const char* vL = (const char*)&Vs[bb][0];                                     \
    _Pragma("unroll") for (int hf = 0; hf < 2; ++hf) {                            \
      const bf16x8 kg0 = *(const bf16x8*)(kL + koffs[hf][0]);                     \
      const bf16x8 kg1 = *(const bf16x8*)(kL + koffs[hf][1]);                     \
      const bf16x8 kg2 = *(const bf16x8*)(kL + koffs[hf][2]);                     \
      const bf16x8 kg3 = *(const bf16x8*)(kL + koffs[hf][3]);                     \
      f32x4 zA0 = {}, zA1 = {}, zB0 = {}, zB1 = {};                               \
      __builtin_amdgcn_s_setprio(1);                                              \
      zA0 = __builtin_amdgcn_mfma_f32_16x16x32_bf16(kg0, qfA0, zA0, 0, 0, 0);     \
      zA0 = __builtin_amdgcn_mfma_f32_16x16x32_bf16(kg1, qfA1, zA0, 0, 0, 0);     \
      zA1 = __builtin_amdgcn_mfma_f32_16x16x32_bf16(kg2, qfA0, zA1, 0, 0, 0);     \
      zA1 = __builtin_amdgcn_mfma_f32_16x16x32_bf16(kg3, qfA1, zA1, 0, 0, 0);     \
      zB0 = __builtin_amdgcn_mfma_f32_16x16x32_bf16(kg0, qfB0, zB0, 0, 0, 0);     \
      zB0 = __builtin_amdgcn_mfma_f32_16x16x32_bf16(kg1, qfB1, zB0, 0, 0, 0);     \
      zB1 = __builtin_amdgcn_mfma_f32_16x16x32_bf16(kg2, qfB0, zB1, 0, 0, 0);     \
      zB1 = __builtin_amdgcn_mfma_f32_16x16x32_bf16(kg3, qfB1, zB1, 0, 0, 0);     \
      __builtin_amdgcn_s_setprio(0);                                              \
      const int dA = qA - (kb0) - hf * 32 - l4 * 4;                               \
      const int dB = dA + 16;                                                     \
      union { unsigned u[4]; bf16x8 v; } pfA, pfB;                                \
      QTILE_P(zA0, zA1, dA, lsumA, pfA);                                          \
      QTILE_P(zB0, zB1, dB, lsumB, pfB);                                          \
      const bf16x8 v0 = *(const bf16x8*)(vL + voffs[hf][0]);                      \
      const bf16x8 v1 = *(const bf16x8*)(vL + voffs[hf][1]);                      \
      const bf16x8 v2 = *(const bf16x8*)(vL + voffs[hf][2]);                      \
      const bf16x8 v3 = *(const bf16x8*)(vL + voffs[hf][3]);                      \
      __builtin_amdgcn_s_setprio(1);                                              \
      oA[0] = __builtin_amdgcn_mfma_f32_16x16x32_bf16(v0, pfA.v, oA[0], 0, 0, 0); \
      oA[1] = __builtin_amdgcn_mfma_f32_16x16x32_bf16(v1, pfA.v, oA[1], 0, 0, 0); \
      oA[2] = __builtin_amdgcn_mfma_f32_16x16x32_bf16(v2, pfA.v, oA[2], 0, 0, 0); \
      oA[3] = __builtin_amdgcn_mfma_f32_16x16x32_bf16(v3, pfA.v, oA[3], 0, 0, 0); \
      oB[0] = __builtin_amdgcn_mfma_f32_16x16x32_bf16(v0, pfB.v, oB[0], 0, 0, 0); \
      oB[1] = __builtin_amdgcn_mfma_f32_16x16x32_bf16(v1, pfB.v, oB[1], 0, 0, 0); \
      oB[2] = __builtin_amdgcn_mfma_f32_16x16x32_bf16(v2, pfB.v, oB[2], 0, 0, 0); \
      oB[3] = __builtin_amdgcn_mfma_f32_16x16x32_bf16(v3, pfB.v, oB[3], 0, 0, 0); \
      __builtin_amdgcn_s_setprio(0);                                              \
    }                                                                             \
  } while (0)

  STAGE(0, t_lo);
  __syncthreads();
  for (int t = t_lo; t < t_end; ++t) {
    const int bb = (t - t_lo) & 1;
    const int tn = (t + 1 < t_end) ? (t + 1) : t_lo;  // dummy restage on last
    STAGE(bb ^ 1, tn);
    COMPUTE(bb, t * 64);
    __syncthreads();  // staging into bb^1 done; bb free for next STAGE
  }
#undef STAGE
#undef QTILE_P
#undef COMPUTE

  // ---- final row-sums (once) + far count
  lsumA += __shfl_xor(lsumA, 16, 64);
  lsumA += __shfl_xor(lsumA, 32, 64);
  lsumB += __shfl_xor(lsumB, 16, 64);
  lsumB += __shfl_xor(lsumB, 32, 64);
  const float rlA = __builtin_amdgcn_rcpf(lsumA + (float)nfar);
  const float rlB = __builtin_amdgcn_rcpf(lsumB + (float)nfar);

  // ---- epilogue: lane holds O^T[d = di*16 + l4*4 + j][q = l15]
  unsigned short* aopA = ao + (size_t)(b * Tc + qA) * Cc + h * DHc + l4 * 4;
  unsigned short* aopB = ao + (size_t)(b * Tc + qB) * Cc + h * DHc + l4 * 4;
#pragma unroll
  for (int di = 0; di < 4; ++di)
#pragma unroll
    for (int j = 0; j < 4; ++j) {
      aopA[di * 16 + j] = f2bf(oA[di][j] * rlA);
      aopB[di * 16 + j] = f2bf(oB[di][j] * rlB);
    }
}

// ---------------------------------------------------------------- launcher
extern "C" void kernel_launch(void* const* d_in, const int* in_sizes, int n_in,
                              void* d_out, int out_size, void* d_ws, size_t ws_size,
                              hipStream_t stream) {
  const float* x      = (const float*)d_in[0];  // [B,T,C]
  const float* qkv_w  = (const float*)d_in[1];  // [3C,C]
  const float* qkv_b  = (const float*)d_in[2];  // [3C]
  const float* proj_w = (const float*)d_in[3];  // [C,C]
  const float* proj_b = (const float*)d_in[4];  // [C]
  const float* lraw   = (const float*)d_in[5];  // [H]

  // workspace layout (bf16 as unsigned short)
  unsigned short* xb    = (unsigned short*)d_ws;       // 4096*1024   (reused as ao)
  unsigned short* wqkv  = xb + 4194304;                // 3072*1024
  unsigned short* wproj = wqkv + 3145728;              // 1024*1024
  unsigned short* qkvo  = wproj + 1048576;             // 4096*3072
  unsigned short* vt    = qkvo + 12582912;             // 32*64*2048
  float*          vsum  = (float*)(vt + 4194304);      // 32*32*64 f32
  float*          vpre  = vsum + 65536;                // 32*33*64 f32
  unsigned short* ao    = xb;                          // reuse (x dead after GEMM1)

  k_cvt<<<4096, 256, 0, stream>>>(x, xb, 1048576);
  k_cvt<<<3072, 256, 0, stream>>>(qkv_w, wqkv, 786432);
  k_cvt<<<1024, 256, 0, stream>>>(proj_w, wproj, 262144);
  // qkv = x @ qkv_w^T + b  -> bf16 [4096][3072]  (256^2 phase-interleaved)
  k_gemm256<1><<<192, 512, 0, stream>>>(xb, wqkv, qkv_b, qkvo, 1024, 3072, 12);
  // V^T per head + per-tile V sums
  k_vtrans<<<dim3(32, 32), 256, 0, stream>>>(qkvo, vt, vsum);
  // prefix sums over key tiles
  k_prefix<<<32, 64, 0, stream>>>(vsum, vpre);
  // decay attention -> bf16 [4096][1024]
  k_attn<<<512, 256, 0, stream>>>(qkvo, vt, lraw, vpre, ao);
  // out = attn_out @ proj_w^T + b -> f32 d_out
  k_gemm_nt<0><<<dim3(8, 32), 256, 0, stream>>>(ao, wproj, proj_b, d_out, 1024, 1024);
}

// Round 9
// 178.805 us; speedup vs baseline: 1.0541x; 1.0541x over previous
//
#include <hip/hip_runtime.h>
#include <cstdint>
#include <cstddef>

// DecayAttention: B=2, T=2048, C=1024, H=16, DH=64
// out = proj( softmax( (QK^T * scale) * exp(-softplus(lambda_h)*|i-j|) ) V )

#define DEVI __device__ __forceinline__

typedef float f32x4 __attribute__((ext_vector_type(4)));
typedef short bf16x8 __attribute__((ext_vector_type(8)));

static constexpr int Bc = 2, Tc = 2048, Cc = 1024, Hc = 16, DHc = 64;

DEVI unsigned short f2bf(float f) {
  union { float f; unsigned u; } a; a.f = f;
  unsigned u = a.u;
  unsigned r = (u + 0x7fffu + ((u >> 16) & 1u)) >> 16;  // RNE
  return (unsigned short)r;
}

DEVI float bf2f(unsigned short u) {
  union { unsigned u; float f; } a; a.u = ((unsigned)u) << 16;
  return a.f;
}

DEVI unsigned packbf(float lo, float hi) {
  return (unsigned)f2bf(lo) | ((unsigned)f2bf(hi) << 16);
}

DEVI void gload_lds16(const void* g, void* l) {
  __builtin_amdgcn_global_load_lds(
      (const __attribute__((address_space(1))) void*)g,
      (__attribute__((address_space(3))) void*)l, 16, 0, 0);
}

// ---------------------------------------------------------------- f32 -> bf16
__global__ __launch_bounds__(256) void k_cvt(const float* __restrict__ in,
                                             unsigned short* __restrict__ out,
                                             int n4) {
  int i = blockIdx.x * 256 + threadIdx.x;
  if (i >= n4) return;
  const float4 v = ((const float4*)in)[i];
  ushort4 o;
  o.x = f2bf(v.x); o.y = f2bf(v.y); o.z = f2bf(v.z); o.w = f2bf(v.w);
  ((ushort4*)out)[i] = o;
}

// -------------------- 128x128 NT GEMM, 4 waves, BK=64, 2-phase, 1 barrier/tile
// C = A * B^T + bias. Wave tile 64x64 -> per phase a 4x4 cluster of 16x16x32:
// 8 ds_read_b128 feed 16 MFMA (0.5 reads/MFMA). LDS 64 KiB -> 2 blocks/CU, the
// second block covers barrier/vmcnt stalls.
// Race-freedom: stages for tile t+1 (into dbuf^1, all 8 gloads) issue in
// phase 1 of tile t, AFTER the phase-2(t-1) barrier at which every wave had
// lgkm0-drained its reads of dbuf^1. Phase 2 does lgkm0 (own ds_reads) +
// vmcnt(0) (own stages) BEFORE its barrier, so after that barrier the whole
// staged tile is visible and all reads of dbuf are complete.
// T2 swizzle: LDS 16B-unit (row,u) holds global unit (row, u^(row&7)); linear
// gload_lds dest + pre-swizzled global source; ds_read applies the same XOR.
template <int OUT_BF16>
__global__ __launch_bounds__(256, 2) void k_gemm128(
    const unsigned short* __restrict__ A, const unsigned short* __restrict__ B,
    const float* __restrict__ bias, void* __restrict__ C,
    int K, int ldc, int NB) {
  __shared__ __align__(16) unsigned short AS[2][8192];  // [dbuf][128 rows x 64 k]
  __shared__ __align__(16) unsigned short BS[2][8192];
  const int tid = threadIdx.x, lane = tid & 63, wid = tid >> 6;
  const int wm = wid >> 1, wn = wid & 1;
  const int l15 = lane & 15, l4 = lane >> 4;
  // XCD-aware swizzle (gridDim.x % 8 == 0)
  const int swz = (blockIdx.x & 7) * (gridDim.x >> 3) + (blockIdx.x >> 3);
  const int blockM = (swz / NB) * 128, blockN = (swz % NB) * 128;

  // staging: 4 gload rounds for A + 4 for B per tile (unit = 16B = 8 bf16)
  const unsigned short* aS[4];
  const unsigned short* bS[4];
  int ldsOff[4];
#pragma unroll
  for (int g = 0; g < 4; ++g) {
    const int u = g * 256 + tid;              // 0..1023
    const int row = u >> 3;
    const int wu = (u & 7) ^ (row & 7);       // pre-swizzled source unit
    aS[g] = A + (size_t)(blockM + row) * K + wu * 8;
    bS[g] = B + (size_t)(blockN + row) * K + wu * 8;
    ldsOff[g] = u * 16;                        // linear LDS byte offset
  }
  const int T = K >> 6;

#define SG(d, t)                                                               \
  do {                                                                         \
    _Pragma("unroll") for (int g = 0; g < 4; ++g) {                            \
      gload_lds16(aS[g] + (t) * 64, (char*)&AS[d][0] + ldsOff[g]);             \
      gload_lds16(bS[g] + (t) * 64, (char*)&BS[d][0] + ldsOff[g]);             \
    }                                                                          \
  } while (0)

  // ds_read byte offsets (swizzle-inverted), loop-invariant
  int aoff[4][2], boff[4][2];
#pragma unroll
  for (int mt = 0; mt < 4; ++mt)
#pragma unroll
    for (int kh = 0; kh < 2; ++kh) {
      const int r = wm * 64 + mt * 16 + l15;
      aoff[mt][kh] = r * 128 + (((kh * 4 + l4) ^ (r & 7)) * 16);
    }
#pragma unroll
  for (int nt = 0; nt < 4; ++nt)
#pragma unroll
    for (int kh = 0; kh < 2; ++kh) {
      const int r = wn * 64 + nt * 16 + l15;
      boff[nt][kh] = r * 128 + (((kh * 4 + l4) ^ (r & 7)) * 16);
    }

  f32x4 acc[4][4] = {};

  // prologue: stage tile 0, drain, sync
  SG(0, 0);
  asm volatile("s_waitcnt vmcnt(0)" ::: "memory");
  __builtin_amdgcn_s_barrier();
  __builtin_amdgcn_sched_barrier(0);

  for (int t = 0; t < T; ++t) {
    const int d = t & 1;
    // ---- phase 1 (kh=0): reads buf d; issues stages for t+1 into buf d^1
    {
      const char* aL = (const char*)&AS[d][0];
      const char* bL = (const char*)&BS[d][0];
      bf16x8 af[4], bf[4];
#pragma unroll
      for (int mt = 0; mt < 4; ++mt) af[mt] = *(const bf16x8*)(aL + aoff[mt][0]);
#pragma unroll
      for (int nt = 0; nt < 4; ++nt) bf[nt] = *(const bf16x8*)(bL + boff[nt][0]);
      if (t + 1 < T) SG(d ^ 1, t + 1);
      __builtin_amdgcn_s_setprio(1);
#pragma unroll
      for (int mt = 0; mt < 4; ++mt)
#pragma unroll
        for (int nt = 0; nt < 4; ++nt)
          acc[mt][nt] = __builtin_amdgcn_mfma_f32_16x16x32_bf16(af[mt], bf[nt],
                                                                acc[mt][nt], 0, 0, 0);
      __builtin_amdgcn_s_setprio(0);
    }
    // ---- phase 2 (kh=1): reads buf d; lgkm0+vmcnt0+barrier, then MFMA
    {
      const char* aL = (const char*)&AS[d][0];
      const char* bL = (const char*)&BS[d][0];
      bf16x8 af[4], bf[4];
#pragma unroll
      for (int mt = 0; mt < 4; ++mt) af[mt] = *(const bf16x8*)(aL + aoff[mt][1]);
#pragma unroll
      for (int nt = 0; nt < 4; ++nt) bf[nt] = *(const bf16x8*)(bL + boff[nt][1]);
      asm volatile("s_waitcnt vmcnt(0) lgkmcnt(0)" ::: "memory");
      __builtin_amdgcn_s_barrier();
      __builtin_amdgcn_sched_barrier(0);
      __builtin_amdgcn_s_setprio(1);
#pragma unroll
      for (int mt = 0; mt < 4; ++mt)
#pragma unroll
        for (int nt = 0; nt < 4; ++nt)
          acc[mt][nt] = __builtin_amdgcn_mfma_f32_16x16x32_bf16(af[mt], bf[nt],
                                                                acc[mt][nt], 0, 0, 0);
      __builtin_amdgcn_s_setprio(0);
    }
  }
#undef SG

  // epilogue: D col = l15, row = l4*4 + j
#pragma unroll
  for (int mt = 0; mt < 4; ++mt) {
    const int r0 = blockM + wm * 64 + mt * 16 + l4 * 4;
#pragma unroll
    for (int nt = 0; nt < 4; ++nt) {
      const int c = blockN + wn * 64 + nt * 16 + l15;
      const float bv = bias[c];
#pragma unroll
      for (int j = 0; j < 4; ++j) {
        const float v = acc[mt][nt][j] + bv;
        if (OUT_BF16)
          ((unsigned short*)C)[(size_t)(r0 + j) * ldc + c] = f2bf(v);
        else
          ((float*)C)[(size_t)(r0 + j) * ldc + c] = v;
      }
    }
  }
}

// --------- V transpose: [B,T,H,DH] -> [B,H,DH,T], plus per-64-key-tile V sums
__global__ __launch_bounds__(256) void k_vtrans(const unsigned short* __restrict__ qkv,
                                                unsigned short* __restrict__ vt,
                                                float* __restrict__ vsum) {
  __shared__ unsigned short tile[64][65];
  __shared__ float psum[4][64];
  const int bh = blockIdx.y, b = bh >> 4, h = bh & 15;
  const int t0 = blockIdx.x * 64;
  const int tid = threadIdx.x;
#pragma unroll
  for (int r = 0; r < 16; ++r) {
    const int e = r * 256 + tid;
    const int row = e >> 6, col = e & 63;  // row = t offset, col = d
    tile[row][col] = qkv[(size_t)(b * Tc + t0 + row) * (3 * Cc) + 2 * Cc + h * DHc + col];
  }
  __syncthreads();
#pragma unroll
  for (int r = 0; r < 16; ++r) {
    const int e = r * 256 + tid;
    const int dd = e >> 6, tcol = e & 63;
    vt[((size_t)bh * DHc + dd) * Tc + t0 + tcol] = tile[tcol][dd];
  }
  // per-tile V column sums (for far-field prefix)
  const int d = tid & 63, part = tid >> 6;
  float s = 0.f;
#pragma unroll
  for (int k = 0; k < 16; ++k) s += bf2f(tile[part * 16 + k][d]);
  psum[part][d] = s;
  __syncthreads();
  if (tid < 64)
    vsum[((size_t)bh * 32 + blockIdx.x) * 64 + tid] =
        psum[0][tid] + psum[1][tid] + psum[2][tid] + psum[3][tid];
}

// --------------- prefix over key tiles: vpre[bh][t][d] = sum_{k<64t} V[k][d]
__global__ __launch_bounds__(64) void k_prefix(const float* __restrict__ vsum,
                                               float* __restrict__ vpre) {
  const int bh = blockIdx.x, d = threadIdx.x;
  float run = 0.f;
  for (int t = 0; t < 32; ++t) {
    vpre[((size_t)bh * 33 + t) * 64 + d] = run;
    run += vsum[((size_t)bh * 32 + t) * 64 + d];
  }
  vpre[((size_t)bh * 33 + 32) * 64 + d] = run;
}

// --------------------------------------------------------- decay attention
// R7 structure (unchanged): far-field cutoff + LDS-staged K/V + swapped-operand
// S^T = mfma(K,Q) + P^T->B-frag via shuffles + no max-subtraction.
__global__ __launch_bounds__(256, 2) void k_attn(const unsigned short* __restrict__ qkv,
                                                 const unsigned short* __restrict__ vt,
                                                 const float* __restrict__ lraw,
                                                 const float* __restrict__ vpre,
                                                 unsigned short* __restrict__ ao) {
  __shared__ __align__(16) unsigned short Ks[2][4096];  // [64 keys][64 d] swz
  __shared__ __align__(16) unsigned short Vs[2][4096];  // [64 d][64 keys] swz
  const int tid = threadIdx.x, lane = tid & 63, wid = tid >> 6;
  const int l15 = lane & 15, l4 = lane >> 4;
  const int bid = blockIdx.x;
  const int xcd = bid & 7, jj = bid >> 3;
  const int bh = xcd + 8 * (jj >> 4);   // 0..31
  const int qblk = jj & 15;             // 0..15
  const int b = bh >> 4, h = bh & 15;
  const float lam = log1pf(__expf(lraw[h]));  // softplus
  const int qt0 = qblk * 8 + wid * 2;   // wave's q-tiles: qt0, qt0+1
  const int qA = qt0 * 16 + l15, qB = qA + 16;

  // ---- far-field band
  const int Dstar = (int)fminf(2048.0f, ceilf(18.5f / lam));
  const int q0 = qblk * 128;
  const int t_lo = (q0 > Dstar) ? ((q0 - Dstar) >> 6) : 0;
  const int t_end = min(32, (q0 + Dstar + 191) >> 6);  // first fully-far upper tile
  const int nfar = 64 * t_lo + (Tc - 64 * t_end);      // keys with p == 1 exactly

  // Q fragments (B-operand): col=q (l15), k=d=l4*8+j
  const unsigned short* qpA = qkv + (size_t)(b * Tc + qA) * (3 * Cc) + h * DHc + l4 * 8;
  const unsigned short* qpB = qkv + (size_t)(b * Tc + qB) * (3 * Cc) + h * DHc + l4 * 8;
  const bf16x8 qfA0 = *(const bf16x8*)qpA, qfA1 = *(const bf16x8*)(qpA + 32);
  const bf16x8 qfB0 = *(const bf16x8*)qpB, qfB1 = *(const bf16x8*)(qpB + 32);

  // ---- staging source pointers (per-lane, pre-swizzled global addresses)
  const unsigned short* kSrc[2];
  const unsigned short* vSrc[2];
#pragma unroll
  for (int rr = 0; rr < 2; ++rr) {
    const int slot = (rr * 4 + wid) * 64 + lane;  // 0..511
    const int row = slot >> 3, wu = slot & 7;
    kSrc[rr] = qkv + (size_t)(b * Tc + row) * (3 * Cc) + Cc + h * DHc + 8 * (wu ^ (row & 7));
    vSrc[rr] = vt + (size_t)(bh * DHc + row) * Tc + 8 * (wu ^ (row & 7));
  }
  constexpr size_t KTS = (size_t)64 * 3 * Cc;  // K elems per 64-key tile
  int koffs[2][4], voffs[2][4];
#pragma unroll
  for (int hf = 0; hf < 2; ++hf) {
    const int r0 = hf * 32 + l15, r1 = r0 + 16;
    koffs[hf][0] = r0 * 128 + ((l4 ^ (r0 & 7)) * 16);
    koffs[hf][1] = r0 * 128 + (((4 + l4) ^ (r0 & 7)) * 16);
    koffs[hf][2] = r1 * 128 + ((l4 ^ (r1 & 7)) * 16);
    koffs[hf][3] = r1 * 128 + (((4 + l4) ^ (r1 & 7)) * 16);
#pragma unroll
    for (int db = 0; db < 4; ++db) {
      const int rv = db * 16 + l15;
      voffs[hf][db] = rv * 128 + (((hf * 4 + l4) ^ (rv & 7)) * 16);
    }
  }

  const int src0 = l15 | ((l4 & 1) << 5);
  const bool hi = (l4 >= 2);

  // ---- seed O with far-field V sums (weight exactly 1), lsum with far count
  f32x4 oA[4], oB[4];
  {
    const float* pre_lo = vpre + ((size_t)bh * 33 + t_lo) * 64;
    const float* pre_hi = vpre + ((size_t)bh * 33 + t_end) * 64;
    const float* pre_all = vpre + ((size_t)bh * 33 + 32) * 64;
#pragma unroll
    for (int di = 0; di < 4; ++di)
#pragma unroll
      for (int j = 0; j < 4; ++j) {
        const int d = di * 16 + l4 * 4 + j;
        const float far = pre_lo[d] + (pre_all[d] - pre_hi[d]);
        oA[di][j] = far;
        oB[di][j] = far;
      }
  }
  float lsumA = 0.f, lsumB = 0.f;

#define STAGE(bb, t)                                                          \
  do {                                                                        \
    _Pragma("unroll") for (int rr = 0; rr < 2; ++rr) {                        \
      gload_lds16(kSrc[rr] + (size_t)(t) * KTS, &Ks[bb][(rr * 4 + wid) * 512]); \
      gload_lds16(vSrc[rr] + (t) * 64, &Vs[bb][(rr * 4 + wid) * 512]);        \
    }                                                                         \
  } while (0)

#define QTILE_P(zz0, zz1, delta_, lsum_, pf_)                                 \
  do {                                                                        \
    float p0[4], p1[4];                                                       \
    _Pragma("unroll") for (int r = 0; r < 4; ++r) {                           \
      const float d0 = 0.125f * __expf(-lam * (float)abs((delta_) - r));      \
      const float d1 = 0.125f * __expf(-lam * (float)abs((delta_) - 16 - r)); \
      p0[r] = __expf(zz0[r] * d0);                                            \
      p1[r] = __expf(zz1[r] * d1);                                            \
      lsum_ += p0[r] + p1[r];                                                 \
    }                                                                         \
    const unsigned pk00 = packbf(p0[0], p0[1]);                               \
    const unsigned pk01 = packbf(p0[2], p0[3]);                               \
    const unsigned pk10 = packbf(p1[0], p1[1]);                               \
    const unsigned pk11 = packbf(p1[2], p1[3]);                               \
    const unsigned a0 = __shfl(pk00, src0, 64), b0 = __shfl(pk10, src0, 64);  \
    const unsigned a1 = __shfl(pk01, src0, 64), b1 = __shfl(pk11, src0, 64);  \
    const unsigned a2 = __shfl(pk00, src0 + 16, 64),                          \
                   b2 = __shfl(pk10, src0 + 16, 64);                          \
    const unsigned a3 = __shfl(pk01, src0 + 16, 64),                          \
                   b3 = __shfl(pk11, src0 + 16, 64);                          \
    pf_.u[0] = hi ? b0 : a0;                                                  \
    pf_.u[1] = hi ? b1 : a1;                                                  \
    pf_.u[2] = hi ? b2 : a2;                                                  \
    pf_.u[3] = hi ? b3 : a3;                                                  \
  } while (0)

#define COMPUTE(bb, kb0)                                                          \
  do {                                                                            \
    const char* kL = (const char*)&Ks[bb][0];                                     \
    const char* vL = (const char*)&Vs[bb][0];                                     \
    _Pragma("unroll") for (int hf = 0; hf < 2; ++hf) {                            \
      const bf16x8 kg0 = *(const bf16x8*)(kL + koffs[hf][0]);                     \
      const bf16x8 kg1 = *(const bf16x8*)(kL + koffs[hf][1]);                     \
      const bf16x8 kg2 = *(const bf16x8*)(kL + koffs[hf][2]);                     \
      const bf16x8 kg3 = *(const bf16x8*)(kL + koffs[hf][3]);                     \
      f32x4 zA0 = {}, zA1 = {}, zB0 = {}, zB1 = {};                               \
      __builtin_amdgcn_s_setprio(1);                                              \
      zA0 = __builtin_amdgcn_mfma_f32_16x16x32_bf16(kg0, qfA0, zA0, 0, 0, 0);     \
      zA0 = __builtin_amdgcn_mfma_f32_16x16x32_bf16(kg1, qfA1, zA0, 0, 0, 0);     \
      zA1 = __builtin_amdgcn_mfma_f32_16x16x32_bf16(kg2, qfA0, zA1, 0, 0, 0);     \
      zA1 = __builtin_amdgcn_mfma_f32_16x16x32_bf16(kg3, qfA1, zA1, 0, 0, 0);     \
      zB0 = __builtin_amdgcn_mfma_f32_16x16x32_bf16(kg0, qfB0, zB0, 0, 0, 0);     \
      zB0 = __builtin_amdgcn_mfma_f32_16x16x32_bf16(kg1, qfB1, zB0, 0, 0, 0);     \
      zB1 = __builtin_amdgcn_mfma_f32_16x16x32_bf16(kg2, qfB0, zB1, 0, 0, 0);     \
      zB1 = __builtin_amdgcn_mfma_f32_16x16x32_bf16(kg3, qfB1, zB1, 0, 0, 0);     \
      __builtin_amdgcn_s_setprio(0);                                              \
      const int dA = qA - (kb0) - hf * 32 - l4 * 4;                               \
      const int dB = dA + 16;                                                     \
      union { unsigned u[4]; bf16x8 v; } pfA, pfB;                                \
      QTILE_P(zA0, zA1, dA, lsumA, pfA);                                          \
      QTILE_P(zB0, zB1, dB, lsumB, pfB);                                          \
      const bf16x8 v0 = *(const bf16x8*)(vL + voffs[hf][0]);                      \
      const bf16x8 v1 = *(const bf16x8*)(vL + voffs[hf][1]);                      \
      const bf16x8 v2 = *(const bf16x8*)(vL + voffs[hf][2]);                      \
      const bf16x8 v3 = *(const bf16x8*)(vL + voffs[hf][3]);                      \
      __builtin_amdgcn_s_setprio(1);                                              \
      oA[0] = __builtin_amdgcn_mfma_f32_16x16x32_bf16(v0, pfA.v, oA[0], 0, 0, 0); \
      oA[1] = __builtin_amdgcn_mfma_f32_16x16x32_bf16(v1, pfA.v, oA[1], 0, 0, 0); \
      oA[2] = __builtin_amdgcn_mfma_f32_16x16x32_bf16(v2, pfA.v, oA[2], 0, 0, 0); \
      oA[3] = __builtin_amdgcn_mfma_f32_16x16x32_bf16(v3, pfA.v, oA[3], 0, 0, 0); \
      oB[0] = __builtin_amdgcn_mfma_f32_16x16x32_bf16(v0, pfB.v, oB[0], 0, 0, 0); \
      oB[1] = __builtin_amdgcn_mfma_f32_16x16x32_bf16(v1, pfB.v, oB[1], 0, 0, 0); \
      oB[2] = __builtin_amdgcn_mfma_f32_16x16x32_bf16(v2, pfB.v, oB[2], 0, 0, 0); \
      oB[3] = __builtin_amdgcn_mfma_f32_16x16x32_bf16(v3, pfB.v, oB[3], 0, 0, 0); \
      __builtin_amdgcn_s_setprio(0);                                              \
    }                                                                             \
  } while (0)

  STAGE(0, t_lo);
  __syncthreads();
  for (int t = t_lo; t < t_end; ++t) {
    const int bb = (t - t_lo) & 1;
    const int tn = (t + 1 < t_end) ? (t + 1) : t_lo;  // dummy restage on last
    STAGE(bb ^ 1, tn);
    COMPUTE(bb, t * 64);
    __syncthreads();  // staging into bb^1 done; bb free for next STAGE
  }
#undef STAGE
#undef QTILE_P
#undef COMPUTE

  // ---- final row-sums (once) + far count
  lsumA += __shfl_xor(lsumA, 16, 64);
  lsumA += __shfl_xor(lsumA, 32, 64);
  lsumB += __shfl_xor(lsumB, 16, 64);
  lsumB += __shfl_xor(lsumB, 32, 64);
  const float rlA = __builtin_amdgcn_rcpf(lsumA + (float)nfar);
  const float rlB = __builtin_amdgcn_rcpf(lsumB + (float)nfar);

  // ---- epilogue: lane holds O^T[d = di*16 + l4*4 + j][q = l15]
  unsigned short* aopA = ao + (size_t)(b * Tc + qA) * Cc + h * DHc + l4 * 4;
  unsigned short* aopB = ao + (size_t)(b * Tc + qB) * Cc + h * DHc + l4 * 4;
#pragma unroll
  for (int di = 0; di < 4; ++di)
#pragma unroll
    for (int j = 0; j < 4; ++j) {
      aopA[di * 16 + j] = f2bf(oA[di][j] * rlA);
      aopB[di * 16 + j] = f2bf(oB[di][j] * rlB);
    }
}

// ---------------------------------------------------------------- launcher
extern "C" void kernel_launch(void* const* d_in, const int* in_sizes, int n_in,
                              void* d_out, int out_size, void* d_ws, size_t ws_size,
                              hipStream_t stream) {
  const float* x      = (const float*)d_in[0];  // [B,T,C]
  const float* qkv_w  = (const float*)d_in[1];  // [3C,C]
  const float* qkv_b  = (const float*)d_in[2];  // [3C]
  const float* proj_w = (const float*)d_in[3];  // [C,C]
  const float* proj_b = (const float*)d_in[4];  // [C]
  const float* lraw   = (const float*)d_in[5];  // [H]

  // workspace layout (bf16 as unsigned short)
  unsigned short* xb    = (unsigned short*)d_ws;       // 4096*1024   (reused as ao)
  unsigned short* wqkv  = xb + 4194304;                // 3072*1024
  unsigned short* wproj = wqkv + 3145728;              // 1024*1024
  unsigned short* qkvo  = wproj + 1048576;             // 4096*3072
  unsigned short* vt    = qkvo + 12582912;             // 32*64*2048
  float*          vsum  = (float*)(vt + 4194304);      // 32*32*64 f32
  float*          vpre  = vsum + 65536;                // 32*33*64 f32
  unsigned short* ao    = xb;                          // reuse (x dead after GEMM1)

  k_cvt<<<4096, 256, 0, stream>>>(x, xb, 1048576);
  k_cvt<<<3072, 256, 0, stream>>>(qkv_w, wqkv, 786432);
  k_cvt<<<1024, 256, 0, stream>>>(proj_w, wproj, 262144);
  // qkv = x @ qkv_w^T + b  -> bf16 [4096][3072]
  k_gemm128<1><<<768, 256, 0, stream>>>(xb, wqkv, qkv_b, qkvo, 1024, 3072, 24);
  // V^T per head + per-tile V sums
  k_vtrans<<<dim3(32, 32), 256, 0, stream>>>(qkvo, vt, vsum);
  // prefix sums over key tiles
  k_prefix<<<32, 64, 0, stream>>>(vsum, vpre);
  // decay attention -> bf16 [4096][1024]
  k_attn<<<512, 256, 0, stream>>>(qkvo, vt, lraw, vpre, ao);
  // out = attn_out @ proj_w^T + b -> f32 d_out
  k_gemm128<0><<<256, 256, 0, stream>>>(ao, wproj, proj_b, d_out, 1024, 1024, 8);
}